// Round 2
// baseline (229.658 us; speedup 1.0000x reference)
//
#include <hip/hip_runtime.h>
#include <hip/hip_bf16.h>

#define HWHW 65536   // 256*256
#define LN1E4_32 0.28782313662425572f   // ln(10000)/32
#define TWO_PI_N 6.2831847f              // 2*pi / 1.000001

typedef __attribute__((ext_vector_type(8))) short short8;
typedef __attribute__((ext_vector_type(4))) short s16x4;   // 'short4' taken by HIP
typedef __attribute__((ext_vector_type(4))) float f32x4;

// d_ws layout:
//   [0, 32768)        : wfrag bf16 — Q slots 0..1023 (K=128), K' 1024..1535,
//                       V' 1536..2047 (K=64, pair-summed weights)
//   [32768, 34816)    : bias tables fp32 — peK·Wk+k_b [4][64], then peV·Wv+v_b
//   [65536, 16842752) : feat_supp transposed (B,HW,C) bf16
// REQUIRES ws_size >= 16842752.

__device__ __forceinline__ short f2bf(float f) {
  union { __hip_bfloat16 h; short s; } u;
  u.h = __float2bfloat16(f);
  return u.s;
}

// ---------------- merged pre-pass (R1 version — measured ~BW-floor, keep):
//   blocks 0..2047    : feat_supp (B,C,HW) f32 -> (B,HW,C) bf16 transpose
//   blocks 2048..2055 : weight fragment packing
//   block  2056       : PE-folded bias tables
__global__ __launch_bounds__(256)
void pre_pass(const float* __restrict__ supp,
              const float* __restrict__ qw, const float* __restrict__ kw,
              const float* __restrict__ vw,
              const float* __restrict__ kb, const float* __restrict__ vb,
              __hip_bfloat16* __restrict__ suppT,
              __hip_bfloat16* __restrict__ wfrag, float* __restrict__ bias) {
  const int t = threadIdx.x;
  if (blockIdx.x < 2048) {
    __shared__ short tile[64 * 68];     // 8.7 KB
    const int b   = blockIdx.x >> 10;
    const int p0  = (blockIdx.x & 1023) << 6;
    const int px4 = (t & 15) << 2;      // pixel group 0,4,..,60
    const int g   = t >> 4;             // channel quad 0..15

    const float* src = supp + ((size_t)b * 64 + g * 4) * HWHW + p0 + px4;
    f32x4 v[4];
#pragma unroll
    for (int c = 0; c < 4; ++c)
      v[c] = *(const f32x4*)(src + (size_t)c * HWHW);
#pragma unroll
    for (int j = 0; j < 4; ++j) {
      s16x4 pk;
#pragma unroll
      for (int c = 0; c < 4; ++c) pk[c] = f2bf(v[c][j]);
      *(s16x4*)&tile[(px4 + j) * 68 + g * 4] = pk;
    }
    __syncthreads();
    const int px = t >> 2, ch0 = (t & 3) << 4;
    s16x4 r0 = *(s16x4*)&tile[px * 68 + ch0];
    s16x4 r1 = *(s16x4*)&tile[px * 68 + ch0 + 4];
    s16x4 r2 = *(s16x4*)&tile[px * 68 + ch0 + 8];
    s16x4 r3 = *(s16x4*)&tile[px * 68 + ch0 + 12];
    short8 o0, o1;
#pragma unroll
    for (int j = 0; j < 4; ++j) {
      o0[j] = r0[j]; o0[j + 4] = r1[j];
      o1[j] = r2[j]; o1[j + 4] = r3[j];
    }
    short8* dst = (short8*)(suppT + ((size_t)(b * HWHW + p0 + px)) * 64 + ch0);
    dst[0] = o0;
    dst[1] = o1;
  } else if (blockIdx.x < 2056) {
    // ---- weight fragments. B layout: n=nt*16+(lane&15), k=ks*32+(lane>>4)*8+j
    int slot = (blockIdx.x - 2048) * 256 + t;     // 0..2047
    __hip_bfloat16* dst = wfrag + slot * 8;
    if (slot < 1024) {               // Q (K=128)
      int ksnt = slot >> 6, lane = slot & 63;
      int ks = ksnt >> 2, nt = ksnt & 3;
      const float* w = qw + (nt * 16 + (lane & 15)) * 128 + ks * 32 + (lane >> 4) * 8;
#pragma unroll
      for (int j = 0; j < 8; ++j) dst[j] = __float2bfloat16(w[j]);
    } else {                         // K'/V': K=64, W'[n][c] = W[n][2c]+W[n][2c+1]
      int mat = (slot >= 1536);
      int rem = slot & 511;
      int ksnt = rem >> 6, lane = rem & 63;
      int ks = ksnt >> 2, nt = ksnt & 3;          // ks 0..1
      int c0 = ks * 32 + (lane >> 4) * 8;
      const float* w = (mat ? vw : kw) + (nt * 16 + (lane & 15)) * 128;
#pragma unroll
      for (int j = 0; j < 8; ++j)
        dst[j] = __float2bfloat16(w[2 * (c0 + j)] + w[2 * (c0 + j) + 1]);
    }
  } else {
    // ---- bias[mat*256 + uv*64 + c] = b[c] + sum_kk pe[uv][kk] * W[c][kk]
    for (int s = t; s < 512; s += 256) {
      int mat = s >> 8, uv = (s >> 6) & 3, c = s & 63;
      const float* w = (mat ? vw : kw) + c * 128;
      float acc = (mat ? vb : kb)[c];
      for (int kk = 0; kk < 128; ++kk) {
        float val = (kk < 64 ? (float)(uv >> 1) : (float)(uv & 1)) * TWO_PI_N;
        int i = kk & 63, f = i >> 1;
        float arg = val * __expf(-(float)f * LN1E4_32);
        float pe = (i & 1) ? __cosf(arg) : __sinf(arg);
        acc += pe * w[kk];
      }
      bias[s] = acc;
    }
  }
}

// ---------------- main: 64 px/block, 4 waves. NO LDS in compute path.
// R2 restructure: the mt-loop was a serialized dependent chain
//   flow load -> floor -> 2 scattered gathers -> MFMA  (x4, ~latency-bound)
// Now: (a) per-mt flow loads replaced by __shfl of the Q-phase floor()
// results (integer grid base is shared data within the wave); (b) suppT
// gathers are software-pipelined 2-deep: mt=0,1 issued during the Q phase,
// mt+2 refilled right after mt's MFMAs consume its buffer. Steady-state
// vmcnt wait is vmcnt(2) — the gather queue never drains mid-loop.
// waves_per_eu(3,5): min=3 is the proven no-spill allocator budget.
__global__ __attribute__((amdgpu_waves_per_eu(3, 5))) __launch_bounds__(256)
void iw_main(const __hip_bfloat16* __restrict__ suppT, const float* __restrict__ flow,
             const float* __restrict__ feat_curr,
             const short8* __restrict__ wg, const float* __restrict__ bias_g,
             const float* __restrict__ q_b, float* __restrict__ out)
{
  __shared__ float outstage[64 * 65];   // 16.6 KB, padded stride 65

  const int tid = threadIdx.x;
  const int idx = ((blockIdx.x & 7) << 8) | (blockIdx.x >> 3);  // XCD swizzle
  const int b   = idx >> 10;
  const int hw0 = (idx & 1023) << 6;
  const int lane = tid & 63, wv = tid >> 6;
  const int quad = lane >> 4, l15 = lane & 15;
  const int uvl  = l15 & 3;
  const int prow = l15 >> 2;
  const short8* sT = (const short8*)suppT;   // 8 short8 per pixel

  // per-lane inverse dim_t: f = a*16 + quad*4 + jj
  float invd[2][4];
#pragma unroll
  for (int a = 0; a < 2; ++a)
#pragma unroll
    for (int jj = 0; jj < 4; ++jj)
      invd[a][jj] = __expf(-(float)(a * 16 + quad * 4 + jj) * LN1E4_32);

  int iy, ix;              // integer grid base of this lane's Q pixel
  short8 ka[2][2];         // 2-deep gather pipeline (16 VGPR)
  f32x4 qacc[4];

  // ---------- Q phase: A-frag (m = l15 -> pixel), GEMM (K=128), B from global
  {
    short8 qwf[16];
#pragma unroll
    for (int i = 0; i < 16; ++i) qwf[i] = wg[i * 64 + lane];

    const int qpix = hw0 + wv * 16 + l15;
    float2 fl = ((const float2*)flow)[b * HWHW + qpix];
    float gy = (float)(qpix >> 8) + fl.y;
    float gx = (float)(qpix & 255) + fl.x;
    float fy = floorf(gy), fx = floorf(gx);
    iy = (int)fy; ix = (int)fx;
    float vy = (gy - fy) * (6.2831853071795864f / 2.000001f);
    float vx = (gx - fx) * (6.2831853071795864f / 2.000001f);

    short8 qa[4];
#pragma unroll
    for (int ks = 0; ks < 4; ++ks) {
      float val = (ks < 2) ? vy : vx;
#pragma unroll
      for (int jj = 0; jj < 4; ++jj) {
        int c = ks * 16 + quad * 4 + jj;
        float feat = feat_curr[(b * 64 + c) * HWHW + qpix];
        float arg = val * invd[ks & 1][jj];
        qa[ks][jj * 2]     = f2bf(feat + __sinf(arg));
        qa[ks][jj * 2 + 1] = f2bf(feat + __cosf(arg));
      }
    }

    // prefetch mt=0,1 gathers: addresses via shfl of (iy,ix) — no flow reload.
    // Issued after the feat_curr loads so the Q-MFMA wait leaves these in flight.
#pragma unroll
    for (int pm = 0; pm < 2; ++pm) {
      int p  = pm * 4 + prow;
      int yy = min(max(__shfl(iy, p) + (uvl >> 1), 0), 255);
      int xx = min(max(__shfl(ix, p) + (uvl & 1), 0), 255);
      size_t base = (size_t)(b * HWHW + yy * 256 + xx) * 8;
      ka[pm][0] = sT[base + quad];
      ka[pm][1] = sT[base + 4 + quad];
    }

#pragma unroll
    for (int nt = 0; nt < 4; ++nt) qacc[nt] = (f32x4){0.f, 0.f, 0.f, 0.f};
#pragma unroll
    for (int ks = 0; ks < 4; ++ks)
#pragma unroll
      for (int nt = 0; nt < 4; ++nt)
        qacc[nt] = __builtin_amdgcn_mfma_f32_16x16x32_bf16(
            qa[ks], qwf[ks * 4 + nt], qacc[nt], 0, 0, 0);
  }

  // bias+scale then shuffle-transpose: qT[mt][nt] = q[pixel mt*4+quad][nt*16+l15]
  float qT[4][4];
  {
#pragma unroll
    for (int nt = 0; nt < 4; ++nt) {
      float qb = q_b[nt * 16 + l15];
#pragma unroll
      for (int r = 0; r < 4; ++r)
        qacc[nt][r] = (qacc[nt][r] + qb) * 0.35355339059327373f;
    }
#pragma unroll
    for (int mt = 0; mt < 4; ++mt)
#pragma unroll
      for (int nt = 0; nt < 4; ++nt) {
        int src = mt * 16 + l15;
        float v0 = __shfl(qacc[nt][0], src);
        float v1 = __shfl(qacc[nt][1], src);
        float v2 = __shfl(qacc[nt][2], src);
        float v3 = __shfl(qacc[nt][3], src);
        float t0 = (quad & 2) ? v2 : v0;
        float t1 = (quad & 2) ? v3 : v1;
        qT[mt][nt] = (quad & 1) ? t1 : t0;
      }
  }

  // PE-folded K/V biases (regs): kbr[r][nt] for output row uv=r, c=nt*16+l15
  float kbr[4][4], vbr[4][4];
#pragma unroll
  for (int r = 0; r < 4; ++r)
#pragma unroll
    for (int nt = 0; nt < 4; ++nt) {
      kbr[r][nt] = bias_g[r * 64 + nt * 16 + l15];
      vbr[r][nt] = bias_g[256 + r * 64 + nt * 16 + l15];
    }

  // K'/V' B-fragments: per-lane-fixed -> hoist to registers (64 VGPRs)
  short8 kf[8], vf[8];
#pragma unroll
  for (int i = 0; i < 8; ++i) {
    kf[i] = wg[1024 + i * 64 + lane];
    vf[i] = wg[1536 + i * 64 + lane];
  }

  // ---------- K/V + attention, 4 pixels-per-lane per mt iteration (K-dim 64)
#pragma unroll
  for (int mt = 0; mt < 4; ++mt) {
    short8 ka0 = ka[mt & 1][0];
    short8 ka1 = ka[mt & 1][1];

    f32x4 kacc[4], vacc[4];
#pragma unroll
    for (int nt = 0; nt < 4; ++nt) {
      kacc[nt] = (f32x4){0.f, 0.f, 0.f, 0.f};
      vacc[nt] = (f32x4){0.f, 0.f, 0.f, 0.f};
    }
#pragma unroll
    for (int nt = 0; nt < 4; ++nt) {
      kacc[nt] = __builtin_amdgcn_mfma_f32_16x16x32_bf16(ka0, kf[nt],     kacc[nt], 0, 0, 0);
      vacc[nt] = __builtin_amdgcn_mfma_f32_16x16x32_bf16(ka0, vf[nt],     vacc[nt], 0, 0, 0);
      kacc[nt] = __builtin_amdgcn_mfma_f32_16x16x32_bf16(ka1, kf[4 + nt], kacc[nt], 0, 0, 0);
      vacc[nt] = __builtin_amdgcn_mfma_f32_16x16x32_bf16(ka1, vf[4 + nt], vacc[nt], 0, 0, 0);
    }

    // refill the pipeline: issue mt+2's gathers now; they land during the
    // softmax below plus the whole of iteration mt+1.
    if (mt < 2) {
      int p  = (mt + 2) * 4 + prow;
      int yy = min(max(__shfl(iy, p) + (uvl >> 1), 0), 255);
      int xx = min(max(__shfl(ix, p) + (uvl & 1), 0), 255);
      size_t base = (size_t)(b * HWHW + yy * 256 + xx) * 8;
      ka[mt & 1][0] = sT[base + quad];
      ka[mt & 1][1] = sT[base + 4 + quad];
    }

    // D rows: pixel = mt*4+quad, uv = reg r. Head channels span 8 lanes -> xor reduce.
#pragma unroll
    for (int nt = 0; nt < 4; ++nt) {
      float lg[4];
#pragma unroll
      for (int r = 0; r < 4; ++r) {
        float p = qT[mt][nt] * (kacc[nt][r] + kbr[r][nt]);
        p += __shfl_xor(p, 1);
        p += __shfl_xor(p, 2);
        p += __shfl_xor(p, 4);
        lg[r] = p;
      }
      float mx = fmaxf(fmaxf(lg[0], lg[1]), fmaxf(lg[2], lg[3]));
      float e0 = __expf(lg[0] - mx), e1 = __expf(lg[1] - mx);
      float e2 = __expf(lg[2] - mx), e3 = __expf(lg[3] - mx);
      float inv = 1.0f / (e0 + e1 + e2 + e3);
      float o = (e0 * (vacc[nt][0] + vbr[0][nt]) + e1 * (vacc[nt][1] + vbr[1][nt]) +
                 e2 * (vacc[nt][2] + vbr[2][nt]) + e3 * (vacc[nt][3] + vbr[3][nt])) * inv;
      outstage[(nt * 16 + l15) * 65 + wv * 16 + mt * 4 + quad] = o;
    }
  }

  // ---------- coalesced full-line write-out
  __syncthreads();
#pragma unroll
  for (int i = 0; i < 16; ++i) {
    int j = i * 256 + tid;
    int c = j >> 6, p = j & 63;
    out[(b * 64 + c) * HWHW + hw0 + p] = outstage[c * 65 + p];
  }
}

extern "C" void kernel_launch(void* const* d_in, const int* in_sizes, int n_in,
                              void* d_out, int out_size, void* d_ws, size_t ws_size,
                              hipStream_t stream) {
  const float* feat_supp = (const float*)d_in[0];
  const float* flow      = (const float*)d_in[1];
  const float* feat_curr = (const float*)d_in[2];
  const float* q_w = (const float*)d_in[3];
  const float* q_b = (const float*)d_in[4];
  const float* k_w = (const float*)d_in[5];
  const float* k_b = (const float*)d_in[6];
  const float* v_w = (const float*)d_in[7];
  const float* v_b = (const float*)d_in[8];
  float* out = (float*)d_out;
  (void)in_sizes; (void)n_in; (void)out_size; (void)ws_size;

  __hip_bfloat16* wfrag = (__hip_bfloat16*)d_ws;
  float* bias           = (float*)((char*)d_ws + 32768);
  __hip_bfloat16* suppT = (__hip_bfloat16*)((char*)d_ws + 65536);

  hipLaunchKernelGGL(pre_pass, dim3(2057), dim3(256), 0, stream,
                     feat_supp, q_w, k_w, v_w, k_b, v_b, suppT, wfrag, bias);
  hipLaunchKernelGGL(iw_main, dim3(2048), dim3(256), 0, stream,
                     suppT, flow, feat_curr, (const short8*)d_ws, bias, q_b, out);
}

// Round 4
// 183.286 us; speedup vs baseline: 1.2530x; 1.2530x over previous
//
#include <hip/hip_runtime.h>
#include <hip/hip_bf16.h>

#define HWHW 65536   // 256*256
#define LN1E4_32 0.28782313662425572f   // ln(10000)/32
#define TWO_PI_N 6.2831847f              // 2*pi / 1.000001

typedef __attribute__((ext_vector_type(8))) short short8;
typedef __attribute__((ext_vector_type(4))) short s16x4;   // 'short4' taken by HIP
typedef __attribute__((ext_vector_type(4))) float f32x4;

// d_ws layout:
//   [0, 32768)        : wfrag bf16 — Q slots 0..1023 (K=128), K' 1024..1535,
//                       V' 1536..2047 (K=64, pair-summed weights)
//   [32768, 34816)    : bias tables fp32 — peK·Wk+k_b [4][64], then peV·Wv+v_b
//   [65536, 16842752) : feat_supp transposed (B,HW,C) bf16
// REQUIRES ws_size >= 16842752.

__device__ __forceinline__ short f2bf(float f) {
  union { __hip_bfloat16 h; short s; } u;
  u.h = __float2bfloat16(f);
  return u.s;
}

// ---------------- merged pre-pass (R1 version — measured ~BW-floor, keep):
//   blocks 0..2047    : feat_supp (B,C,HW) f32 -> (B,HW,C) bf16 transpose
//   blocks 2048..2055 : weight fragment packing
//   block  2056       : PE-folded bias tables
__global__ __launch_bounds__(256)
void pre_pass(const float* __restrict__ supp,
              const float* __restrict__ qw, const float* __restrict__ kw,
              const float* __restrict__ vw,
              const float* __restrict__ kb, const float* __restrict__ vb,
              __hip_bfloat16* __restrict__ suppT,
              __hip_bfloat16* __restrict__ wfrag, float* __restrict__ bias) {
  const int t = threadIdx.x;
  if (blockIdx.x < 2048) {
    __shared__ short tile[64 * 68];     // 8.7 KB
    const int b   = blockIdx.x >> 10;
    const int p0  = (blockIdx.x & 1023) << 6;
    const int px4 = (t & 15) << 2;      // pixel group 0,4,..,60
    const int g   = t >> 4;             // channel quad 0..15

    const float* src = supp + ((size_t)b * 64 + g * 4) * HWHW + p0 + px4;
    f32x4 v[4];
#pragma unroll
    for (int c = 0; c < 4; ++c)
      v[c] = *(const f32x4*)(src + (size_t)c * HWHW);
#pragma unroll
    for (int j = 0; j < 4; ++j) {
      s16x4 pk;
#pragma unroll
      for (int c = 0; c < 4; ++c) pk[c] = f2bf(v[c][j]);
      *(s16x4*)&tile[(px4 + j) * 68 + g * 4] = pk;
    }
    __syncthreads();
    const int px = t >> 2, ch0 = (t & 3) << 4;
    s16x4 r0 = *(s16x4*)&tile[px * 68 + ch0];
    s16x4 r1 = *(s16x4*)&tile[px * 68 + ch0 + 4];
    s16x4 r2 = *(s16x4*)&tile[px * 68 + ch0 + 8];
    s16x4 r3 = *(s16x4*)&tile[px * 68 + ch0 + 12];
    short8 o0, o1;
#pragma unroll
    for (int j = 0; j < 4; ++j) {
      o0[j] = r0[j]; o0[j + 4] = r1[j];
      o1[j] = r2[j]; o1[j + 4] = r3[j];
    }
    short8* dst = (short8*)(suppT + ((size_t)(b * HWHW + p0 + px)) * 64 + ch0);
    dst[0] = o0;
    dst[1] = o1;
  } else if (blockIdx.x < 2056) {
    // ---- weight fragments. B layout: n=nt*16+(lane&15), k=ks*32+(lane>>4)*8+j
    int slot = (blockIdx.x - 2048) * 256 + t;     // 0..2047
    __hip_bfloat16* dst = wfrag + slot * 8;
    if (slot < 1024) {               // Q (K=128)
      int ksnt = slot >> 6, lane = slot & 63;
      int ks = ksnt >> 2, nt = ksnt & 3;
      const float* w = qw + (nt * 16 + (lane & 15)) * 128 + ks * 32 + (lane >> 4) * 8;
#pragma unroll
      for (int j = 0; j < 8; ++j) dst[j] = __float2bfloat16(w[j]);
    } else {                         // K'/V': K=64, W'[n][c] = W[n][2c]+W[n][2c+1]
      int mat = (slot >= 1536);
      int rem = slot & 511;
      int ksnt = rem >> 6, lane = rem & 63;
      int ks = ksnt >> 2, nt = ksnt & 3;          // ks 0..1
      int c0 = ks * 32 + (lane >> 4) * 8;
      const float* w = (mat ? vw : kw) + (nt * 16 + (lane & 15)) * 128;
#pragma unroll
      for (int j = 0; j < 8; ++j)
        dst[j] = __float2bfloat16(w[2 * (c0 + j)] + w[2 * (c0 + j) + 1]);
    }
  } else {
    // ---- bias[mat*256 + uv*64 + c] = b[c] + sum_kk pe[uv][kk] * W[c][kk]
    for (int s = t; s < 512; s += 256) {
      int mat = s >> 8, uv = (s >> 6) & 3, c = s & 63;
      const float* w = (mat ? vw : kw) + c * 128;
      float acc = (mat ? vb : kb)[c];
      for (int kk = 0; kk < 128; ++kk) {
        float val = (kk < 64 ? (float)(uv >> 1) : (float)(uv & 1)) * TWO_PI_N;
        int i = kk & 63, f = i >> 1;
        float arg = val * __expf(-(float)f * LN1E4_32);
        float pe = (i & 1) ? __cosf(arg) : __sinf(arg);
        acc += pe * w[kk];
      }
      bias[s] = acc;
    }
  }
}

// ---------------- main: 64 px/block, 4 waves. NO LDS in compute path.
// R3 (resubmit — R3 bench was an infra failure, kernel never ran):
// R2's prefetch spilled (WRITE_SIZE 32->152 MB) because it spanned the
// Q phase where qwf[16] (64 regs) peaks — total demand blew the 168-reg
// budget that waves_per_eu min=3 caps (VGPR 84 + ~84 AGPR, unified file).
// Now: (a) gather offsets off[4] precomputed ONCE after Q-MFMAs via __shfl
// of the Q-phase floor() results (no flow loads in the loop); (b) 1-deep
// gather prefetch scoped strictly after the Q phase (qwf dead); (c) paid
// for by per-nt accumulator restructure: one nt's K/V MFMAs feed its
// softmax immediately — live accumulators 32->8 regs, and the PE-folded
// bias rides in the MFMA C-operand init (reg r == uv row), deleting 32
// v_add per iter.
__global__ __attribute__((amdgpu_waves_per_eu(3, 5))) __launch_bounds__(256)
void iw_main(const __hip_bfloat16* __restrict__ suppT, const float* __restrict__ flow,
             const float* __restrict__ feat_curr,
             const short8* __restrict__ wg, const float* __restrict__ bias_g,
             const float* __restrict__ q_b, float* __restrict__ out)
{
  __shared__ float outstage[64 * 65];   // 16.6 KB, padded stride 65

  const int tid = threadIdx.x;
  const int idx = ((blockIdx.x & 7) << 8) | (blockIdx.x >> 3);  // XCD swizzle
  const int b   = idx >> 10;
  const int hw0 = (idx & 1023) << 6;
  const int lane = tid & 63, wv = tid >> 6;
  const int quad = lane >> 4, l15 = lane & 15;
  const int uvl  = l15 & 3;
  const int prow = l15 >> 2;
  const short8* sT = (const short8*)suppT;   // 8 short8 per pixel

  // per-lane inverse dim_t: f = a*16 + quad*4 + jj
  float invd[2][4];
#pragma unroll
  for (int a = 0; a < 2; ++a)
#pragma unroll
    for (int jj = 0; jj < 4; ++jj)
      invd[a][jj] = __expf(-(float)(a * 16 + quad * 4 + jj) * LN1E4_32);

  int iy, ix;              // integer grid base of this lane's Q pixel
  f32x4 qacc[4];

  // ---------- Q phase: A-frag (m = l15 -> pixel), GEMM (K=128), B from global
  {
    short8 qwf[16];
#pragma unroll
    for (int i = 0; i < 16; ++i) qwf[i] = wg[i * 64 + lane];

    const int qpix = hw0 + wv * 16 + l15;
    float2 fl = ((const float2*)flow)[b * HWHW + qpix];
    float gy = (float)(qpix >> 8) + fl.y;
    float gx = (float)(qpix & 255) + fl.x;
    float fy = floorf(gy), fx = floorf(gx);
    iy = (int)fy; ix = (int)fx;
    float vy = (gy - fy) * (6.2831853071795864f / 2.000001f);
    float vx = (gx - fx) * (6.2831853071795864f / 2.000001f);

    short8 qa[4];
#pragma unroll
    for (int ks = 0; ks < 4; ++ks) {
      float val = (ks < 2) ? vy : vx;
#pragma unroll
      for (int jj = 0; jj < 4; ++jj) {
        int c = ks * 16 + quad * 4 + jj;
        float feat = feat_curr[(b * 64 + c) * HWHW + qpix];
        float arg = val * invd[ks & 1][jj];
        qa[ks][jj * 2]     = f2bf(feat + __sinf(arg));
        qa[ks][jj * 2 + 1] = f2bf(feat + __cosf(arg));
      }
    }
#pragma unroll
    for (int nt = 0; nt < 4; ++nt) qacc[nt] = (f32x4){0.f, 0.f, 0.f, 0.f};
#pragma unroll
    for (int ks = 0; ks < 4; ++ks)
#pragma unroll
      for (int nt = 0; nt < 4; ++nt)
        qacc[nt] = __builtin_amdgcn_mfma_f32_16x16x32_bf16(
            qa[ks], qwf[ks * 4 + nt], qacc[nt], 0, 0, 0);
  }  // qwf dead here — low-pressure region begins

  // ---------- gather offsets for all mt, from in-register iy/ix (no flow reloads)
  int off[4];
#pragma unroll
  for (int m = 0; m < 4; ++m) {
    int p  = m * 4 + prow;
    int yy = min(max(__shfl(iy, p) + (uvl >> 1), 0), 255);
    int xx = min(max(__shfl(ix, p) + (uvl & 1), 0), 255);
    off[m] = (b * HWHW + yy * 256 + xx) * 8;
  }
  // prefetch mt=0 gathers — they land during the 32-shfl transpose below
  short8 nka0 = sT[off[0] + quad];
  short8 nka1 = sT[off[0] + 4 + quad];

  // bias+scale then shuffle-transpose: qT[mt][nt] = q[pixel mt*4+quad][nt*16+l15]
  float qT[4][4];
  {
#pragma unroll
    for (int nt = 0; nt < 4; ++nt) {
      float qb = q_b[nt * 16 + l15];
#pragma unroll
      for (int r = 0; r < 4; ++r)
        qacc[nt][r] = (qacc[nt][r] + qb) * 0.35355339059327373f;
    }
#pragma unroll
    for (int mt = 0; mt < 4; ++mt)
#pragma unroll
      for (int nt = 0; nt < 4; ++nt) {
        int src = mt * 16 + l15;
        float v0 = __shfl(qacc[nt][0], src);
        float v1 = __shfl(qacc[nt][1], src);
        float v2 = __shfl(qacc[nt][2], src);
        float v3 = __shfl(qacc[nt][3], src);
        float t0 = (quad & 2) ? v2 : v0;
        float t1 = (quad & 2) ? v3 : v1;
        qT[mt][nt] = (quad & 1) ? t1 : t0;
      }
  }

  // PE-folded K/V biases (regs): kbr[r][nt] for output row uv=r, c=nt*16+l15
  float kbr[4][4], vbr[4][4];
#pragma unroll
  for (int r = 0; r < 4; ++r)
#pragma unroll
    for (int nt = 0; nt < 4; ++nt) {
      kbr[r][nt] = bias_g[r * 64 + nt * 16 + l15];
      vbr[r][nt] = bias_g[256 + r * 64 + nt * 16 + l15];
    }

  // K'/V' B-fragments: per-lane-fixed -> hoist to registers (64 VGPRs)
  short8 kf[8], vf[8];
#pragma unroll
  for (int i = 0; i < 8; ++i) {
    kf[i] = wg[1024 + i * 64 + lane];
    vf[i] = wg[1536 + i * 64 + lane];
  }

  // ---------- K/V + attention, 4 pixels-per-lane per mt iteration (K-dim 64)
#pragma unroll
  for (int mt = 0; mt < 4; ++mt) {
    short8 ka0 = nka0;
    short8 ka1 = nka1;
    // 1-deep prefetch: mt+1's gathers issued now, consumed after this
    // iteration's 16 MFMAs + 4 softmax groups (~500+ cyc of cover).
    if (mt < 3) {
      nka0 = sT[off[mt + 1] + quad];
      nka1 = sT[off[mt + 1] + 4 + quad];
    }

    // per-nt: MFMA pair -> immediate softmax. Only one nt's accumulators
    // live at a time (8 regs); bias pre-loaded into the C-operand.
#pragma unroll
    for (int nt = 0; nt < 4; ++nt) {
      f32x4 kacc = (f32x4){kbr[0][nt], kbr[1][nt], kbr[2][nt], kbr[3][nt]};
      f32x4 vacc = (f32x4){vbr[0][nt], vbr[1][nt], vbr[2][nt], vbr[3][nt]};
      kacc = __builtin_amdgcn_mfma_f32_16x16x32_bf16(ka0, kf[nt],     kacc, 0, 0, 0);
      kacc = __builtin_amdgcn_mfma_f32_16x16x32_bf16(ka1, kf[4 + nt], kacc, 0, 0, 0);
      vacc = __builtin_amdgcn_mfma_f32_16x16x32_bf16(ka0, vf[nt],     vacc, 0, 0, 0);
      vacc = __builtin_amdgcn_mfma_f32_16x16x32_bf16(ka1, vf[4 + nt], vacc, 0, 0, 0);

      // D rows: pixel = mt*4+quad, uv = reg r. Head channels span 8 lanes -> xor reduce.
      float lg[4];
#pragma unroll
      for (int r = 0; r < 4; ++r) {
        float p = qT[mt][nt] * kacc[r];
        p += __shfl_xor(p, 1);
        p += __shfl_xor(p, 2);
        p += __shfl_xor(p, 4);
        lg[r] = p;
      }
      float mx = fmaxf(fmaxf(lg[0], lg[1]), fmaxf(lg[2], lg[3]));
      float e0 = __expf(lg[0] - mx), e1 = __expf(lg[1] - mx);
      float e2 = __expf(lg[2] - mx), e3 = __expf(lg[3] - mx);
      float inv = 1.0f / (e0 + e1 + e2 + e3);
      float o = (e0 * vacc[0] + e1 * vacc[1] + e2 * vacc[2] + e3 * vacc[3]) * inv;
      outstage[(nt * 16 + l15) * 65 + wv * 16 + mt * 4 + quad] = o;
    }
  }

  // ---------- coalesced full-line write-out
  __syncthreads();
#pragma unroll
  for (int i = 0; i < 16; ++i) {
    int j = i * 256 + tid;
    int c = j >> 6, p = j & 63;
    out[(b * 64 + c) * HWHW + hw0 + p] = outstage[c * 65 + p];
  }
}

extern "C" void kernel_launch(void* const* d_in, const int* in_sizes, int n_in,
                              void* d_out, int out_size, void* d_ws, size_t ws_size,
                              hipStream_t stream) {
  const float* feat_supp = (const float*)d_in[0];
  const float* flow      = (const float*)d_in[1];
  const float* feat_curr = (const float*)d_in[2];
  const float* q_w = (const float*)d_in[3];
  const float* q_b = (const float*)d_in[4];
  const float* k_w = (const float*)d_in[5];
  const float* k_b = (const float*)d_in[6];
  const float* v_w = (const float*)d_in[7];
  const float* v_b = (const float*)d_in[8];
  float* out = (float*)d_out;
  (void)in_sizes; (void)n_in; (void)out_size; (void)ws_size;

  __hip_bfloat16* wfrag = (__hip_bfloat16*)d_ws;
  float* bias           = (float*)((char*)d_ws + 32768);
  __hip_bfloat16* suppT = (__hip_bfloat16*)((char*)d_ws + 65536);

  hipLaunchKernelGGL(pre_pass, dim3(2057), dim3(256), 0, stream,
                     feat_supp, q_w, k_w, v_w, k_b, v_b, suppT, wfrag, bias);
  hipLaunchKernelGGL(iw_main, dim3(2048), dim3(256), 0, stream,
                     suppT, flow, feat_curr, (const short8*)d_ws, bias, q_b, out);
}

// Round 5
// 153.147 us; speedup vs baseline: 1.4996x; 1.1968x over previous
//
#include <hip/hip_runtime.h>
#include <hip/hip_bf16.h>

#define HWHW 65536   // 256*256
#define LN1E4_32 0.28782313662425572f   // ln(10000)/32
#define TWO_PI_N 6.2831847f              // 2*pi / 1.000001

typedef __attribute__((ext_vector_type(8))) short short8;
typedef __attribute__((ext_vector_type(4))) short s16x4;   // 'short4' taken by HIP
typedef __attribute__((ext_vector_type(4))) float f32x4;

// d_ws layout:
//   [0, 32768)        : wfrag bf16 — Q slots 0..1023 (K=128), K' 1024..1535,
//                       V' 1536..2047 (K=64, pair-summed weights)
//   [32768, 34816)    : bias tables fp32 — peK·Wk+k_b [4][64], then peV·Wv+v_b
//   [65536, 16842752) : feat_supp transposed (B,HW,C) bf16
// REQUIRES ws_size >= 16842752.

__device__ __forceinline__ short f2bf(float f) {
  union { __hip_bfloat16 h; short s; } u;
  u.h = __float2bfloat16(f);
  return u.s;
}

// ---------------- merged pre-pass (R1 version — measured ~BW-floor, keep):
//   blocks 0..2047    : feat_supp (B,C,HW) f32 -> (B,HW,C) bf16 transpose
//   blocks 2048..2055 : weight fragment packing
//   block  2056       : PE-folded bias tables
__global__ __launch_bounds__(256)
void pre_pass(const float* __restrict__ supp,
              const float* __restrict__ qw, const float* __restrict__ kw,
              const float* __restrict__ vw,
              const float* __restrict__ kb, const float* __restrict__ vb,
              __hip_bfloat16* __restrict__ suppT,
              __hip_bfloat16* __restrict__ wfrag, float* __restrict__ bias) {
  const int t = threadIdx.x;
  if (blockIdx.x < 2048) {
    __shared__ short tile[64 * 68];     // 8.7 KB
    const int b   = blockIdx.x >> 10;
    const int p0  = (blockIdx.x & 1023) << 6;
    const int px4 = (t & 15) << 2;      // pixel group 0,4,..,60
    const int g   = t >> 4;             // channel quad 0..15

    const float* src = supp + ((size_t)b * 64 + g * 4) * HWHW + p0 + px4;
    f32x4 v[4];
#pragma unroll
    for (int c = 0; c < 4; ++c)
      v[c] = *(const f32x4*)(src + (size_t)c * HWHW);
#pragma unroll
    for (int j = 0; j < 4; ++j) {
      s16x4 pk;
#pragma unroll
      for (int c = 0; c < 4; ++c) pk[c] = f2bf(v[c][j]);
      *(s16x4*)&tile[(px4 + j) * 68 + g * 4] = pk;
    }
    __syncthreads();
    const int px = t >> 2, ch0 = (t & 3) << 4;
    s16x4 r0 = *(s16x4*)&tile[px * 68 + ch0];
    s16x4 r1 = *(s16x4*)&tile[px * 68 + ch0 + 4];
    s16x4 r2 = *(s16x4*)&tile[px * 68 + ch0 + 8];
    s16x4 r3 = *(s16x4*)&tile[px * 68 + ch0 + 12];
    short8 o0, o1;
#pragma unroll
    for (int j = 0; j < 4; ++j) {
      o0[j] = r0[j]; o0[j + 4] = r1[j];
      o1[j] = r2[j]; o1[j + 4] = r3[j];
    }
    short8* dst = (short8*)(suppT + ((size_t)(b * HWHW + p0 + px)) * 64 + ch0);
    dst[0] = o0;
    dst[1] = o1;
  } else if (blockIdx.x < 2056) {
    // ---- weight fragments. B layout: n=nt*16+(lane&15), k=ks*32+(lane>>4)*8+j
    int slot = (blockIdx.x - 2048) * 256 + t;     // 0..2047
    __hip_bfloat16* dst = wfrag + slot * 8;
    if (slot < 1024) {               // Q (K=128)
      int ksnt = slot >> 6, lane = slot & 63;
      int ks = ksnt >> 2, nt = ksnt & 3;
      const float* w = qw + (nt * 16 + (lane & 15)) * 128 + ks * 32 + (lane >> 4) * 8;
#pragma unroll
      for (int j = 0; j < 8; ++j) dst[j] = __float2bfloat16(w[j]);
    } else {                         // K'/V': K=64, W'[n][c] = W[n][2c]+W[n][2c+1]
      int mat = (slot >= 1536);
      int rem = slot & 511;
      int ksnt = rem >> 6, lane = rem & 63;
      int ks = ksnt >> 2, nt = ksnt & 3;          // ks 0..1
      int c0 = ks * 32 + (lane >> 4) * 8;
      const float* w = (mat ? vw : kw) + (nt * 16 + (lane & 15)) * 128;
#pragma unroll
      for (int j = 0; j < 8; ++j)
        dst[j] = __float2bfloat16(w[2 * (c0 + j)] + w[2 * (c0 + j) + 1]);
    }
  } else {
    // ---- bias[mat*256 + uv*64 + c] = b[c] + sum_kk pe[uv][kk] * W[c][kk]
    for (int s = t; s < 512; s += 256) {
      int mat = s >> 8, uv = (s >> 6) & 3, c = s & 63;
      const float* w = (mat ? vw : kw) + c * 128;
      float acc = (mat ? vb : kb)[c];
      for (int kk = 0; kk < 128; ++kk) {
        float val = (kk < 64 ? (float)(uv >> 1) : (float)(uv & 1)) * TWO_PI_N;
        int i = kk & 63, f = i >> 1;
        float arg = val * __expf(-(float)f * LN1E4_32);
        float pe = (i & 1) ? __cosf(arg) : __sinf(arg);
        acc += pe * w[kk];
      }
      bias[s] = acc;
    }
  }
}

// ---------------- main: 64 px/block, 4 waves.
// R5: occupancy attack. R0-R4 evidence: all structural changes at fixed
// concurrency were neutral; reported VGPR 84 + ~equal AGPR (unified file)
// = ~168 regs -> hard 3 waves/SIMD. Fix: move ALL weight fragments (Q,
// K', V') + bias tables to LDS, read per-use (ds_read_b128, 64 lanes x
// 16B sequential = conflict-free full-BW). Q-weight LDS area is UNIONED
// with outstage (Q weights die before first outstage write) so LDS stays
// at 34.3 KB -> 4 blocks/CU. waves_per_eu(4,4): 128-reg budget vs ~110
// demand -> 4 waves/SIMD (16/CU, ~50%). Loop is nt-outer/mt-inner so
// weight reads hoist only to nt level (16 regs) while all 8 suppT
// gathers issue up-front and are consumed across nt=0's mt loop.
// Spill tripwire: WRITE_SIZE must stay 32768 KB.
__global__ __attribute__((amdgpu_waves_per_eu(4, 4))) __launch_bounds__(256)
void iw_main(const __hip_bfloat16* __restrict__ suppT, const float* __restrict__ flow,
             const float* __restrict__ feat_curr,
             const short8* __restrict__ wg, const float* __restrict__ bias_g,
             const float* __restrict__ q_b, float* __restrict__ out)
{
  // LDS map: [0,16384) K'/V' frags [16][64] short8
  //          [16384,18432) bias as [mat][nt][l15][r] f32 (b128 per lane)
  //          [18432,35072) UNION{ Q frags [16][64] short8 (Q phase only),
  //                               outstage float[64*65] (post-Q) }
  __shared__ __align__(16) char smem[35072];
  short8* lds_kv   = (short8*)smem;
  f32x4*  lds_bias = (f32x4*)(smem + 16384);
  short8* lds_qw   = (short8*)(smem + 18432);
  float*  outstage = (float*)(smem + 18432);

  const int tid = threadIdx.x;
  const int idx = ((blockIdx.x & 7) << 8) | (blockIdx.x >> 3);  // XCD swizzle
  const int b   = idx >> 10;
  const int hw0 = (idx & 1023) << 6;
  const int lane = tid & 63, wv = tid >> 6;
  const int quad = lane >> 4, l15 = lane & 15;
  const int uvl  = l15 & 3;
  const int prow = l15 >> 2;
  const short8* sT = (const short8*)suppT;   // 8 short8 per pixel

  // ---------- stage weights+bias into LDS (all L2-resident, coalesced)
#pragma unroll
  for (int j = 0; j < 4; ++j) {
    lds_qw[j * 256 + tid] = wg[j * 256 + tid];          // Q slots 0..1023
    lds_kv[j * 256 + tid] = wg[1024 + j * 256 + tid];   // K'/V' slots
  }
  {
    float* bl = (float*)lds_bias;
#pragma unroll
    for (int s_ = 0; s_ < 2; ++s_) {
      int s = s_ * 256 + tid;
      int mat = s >> 8, rem = s & 255, r = rem >> 6, c = rem & 63;
      bl[mat * 256 + (c >> 4) * 64 + (c & 15) * 4 + r] = bias_g[s];
    }
  }
  __syncthreads();

  // per-lane inverse dim_t: f = a*16 + quad*4 + jj
  float invd[2][4];
#pragma unroll
  for (int a = 0; a < 2; ++a)
#pragma unroll
    for (int jj = 0; jj < 4; ++jj)
      invd[a][jj] = __expf(-(float)(a * 16 + quad * 4 + jj) * LN1E4_32);

  int iy, ix;              // integer grid base of this lane's Q pixel
  f32x4 qacc[4];

  // ---------- Q phase: A-frag (m = l15 -> pixel), GEMM (K=128), B from LDS
  {
    const int qpix = hw0 + wv * 16 + l15;
    float2 fl = ((const float2*)flow)[b * HWHW + qpix];
    float gy = (float)(qpix >> 8) + fl.y;
    float gx = (float)(qpix & 255) + fl.x;
    float fy = floorf(gy), fx = floorf(gx);
    iy = (int)fy; ix = (int)fx;
    float vy = (gy - fy) * (6.2831853071795864f / 2.000001f);
    float vx = (gx - fx) * (6.2831853071795864f / 2.000001f);

    short8 qa[4];
#pragma unroll
    for (int ks = 0; ks < 4; ++ks) {
      float val = (ks < 2) ? vy : vx;
#pragma unroll
      for (int jj = 0; jj < 4; ++jj) {
        int c = ks * 16 + quad * 4 + jj;
        float feat = feat_curr[(b * 64 + c) * HWHW + qpix];
        float arg = val * invd[ks & 1][jj];
        qa[ks][jj * 2]     = f2bf(feat + __sinf(arg));
        qa[ks][jj * 2 + 1] = f2bf(feat + __cosf(arg));
      }
    }
#pragma unroll
    for (int nt = 0; nt < 4; ++nt) qacc[nt] = (f32x4){0.f, 0.f, 0.f, 0.f};
#pragma unroll
    for (int ks = 0; ks < 4; ++ks)
#pragma unroll
      for (int nt = 0; nt < 4; ++nt)
        qacc[nt] = __builtin_amdgcn_mfma_f32_16x16x32_bf16(
            qa[ks], lds_qw[(ks * 4 + nt) * 64 + lane], qacc[nt], 0, 0, 0);
  }

  // ---------- gather offsets for all mt, from in-register iy/ix
  int off[4];
#pragma unroll
  for (int m = 0; m < 4; ++m) {
    int p  = m * 4 + prow;
    int yy = min(max(__shfl(iy, p) + (uvl >> 1), 0), 255);
    int xx = min(max(__shfl(ix, p) + (uvl & 1), 0), 255);
    off[m] = (b * HWHW + yy * 256 + xx) * 8;
  }

  // barrier: all waves done reading lds_qw before outstage (same bytes) is
  // written. Drains vmcnt too, so gathers are issued AFTER it.
  __syncthreads();

  // all 8 suppT gathers issued up-front; first consumed after the 64-shfl
  // transpose below + nt=0 weight reads -> deep natural pipeline.
  short8 ka[4][2];
#pragma unroll
  for (int m = 0; m < 4; ++m) {
    ka[m][0] = sT[off[m] + quad];
    ka[m][1] = sT[off[m] + 4 + quad];
  }

  // bias+scale then shuffle-transpose: qT[mt][nt] = q[pixel mt*4+quad][nt*16+l15]
  float qT[4][4];
  {
#pragma unroll
    for (int nt = 0; nt < 4; ++nt) {
      float qb = q_b[nt * 16 + l15];
#pragma unroll
      for (int r = 0; r < 4; ++r)
        qacc[nt][r] = (qacc[nt][r] + qb) * 0.35355339059327373f;
    }
#pragma unroll
    for (int mt = 0; mt < 4; ++mt)
#pragma unroll
      for (int nt = 0; nt < 4; ++nt) {
        int src = mt * 16 + l15;
        float v0 = __shfl(qacc[nt][0], src);
        float v1 = __shfl(qacc[nt][1], src);
        float v2 = __shfl(qacc[nt][2], src);
        float v3 = __shfl(qacc[nt][3], src);
        float t0 = (quad & 2) ? v2 : v0;
        float t1 = (quad & 2) ? v3 : v1;
        qT[mt][nt] = (quad & 1) ? t1 : t0;
      }
  }

  // ---------- K/V + attention. nt outer: weights+bias read once per nt
  // from LDS (16 regs); mt inner consumes the prefetched ka[mt].
#pragma unroll
  for (int nt = 0; nt < 4; ++nt) {
    short8 kf0 = lds_kv[nt * 64 + lane];
    short8 kf1 = lds_kv[(4 + nt) * 64 + lane];
    short8 vf0 = lds_kv[(8 + nt) * 64 + lane];
    short8 vf1 = lds_kv[(12 + nt) * 64 + lane];
    f32x4 kb4 = lds_bias[nt * 16 + l15];        // [0][nt][l15][r]
    f32x4 vb4 = lds_bias[64 + nt * 16 + l15];   // [1][nt][l15][r]

#pragma unroll
    for (int mt = 0; mt < 4; ++mt) {
      f32x4 kacc = kb4;   // bias rides in the MFMA C-operand (reg r == uv r)
      f32x4 vacc = vb4;
      kacc = __builtin_amdgcn_mfma_f32_16x16x32_bf16(ka[mt][0], kf0, kacc, 0, 0, 0);
      kacc = __builtin_amdgcn_mfma_f32_16x16x32_bf16(ka[mt][1], kf1, kacc, 0, 0, 0);
      vacc = __builtin_amdgcn_mfma_f32_16x16x32_bf16(ka[mt][0], vf0, vacc, 0, 0, 0);
      vacc = __builtin_amdgcn_mfma_f32_16x16x32_bf16(ka[mt][1], vf1, vacc, 0, 0, 0);

      // D rows: pixel = mt*4+quad, uv = reg r. Head channels span 8 lanes -> xor reduce.
      float lg[4];
#pragma unroll
      for (int r = 0; r < 4; ++r) {
        float p = qT[mt][nt] * kacc[r];
        p += __shfl_xor(p, 1);
        p += __shfl_xor(p, 2);
        p += __shfl_xor(p, 4);
        lg[r] = p;
      }
      float mx = fmaxf(fmaxf(lg[0], lg[1]), fmaxf(lg[2], lg[3]));
      float e0 = __expf(lg[0] - mx), e1 = __expf(lg[1] - mx);
      float e2 = __expf(lg[2] - mx), e3 = __expf(lg[3] - mx);
      float inv = 1.0f / (e0 + e1 + e2 + e3);
      float o = (e0 * vacc[0] + e1 * vacc[1] + e2 * vacc[2] + e3 * vacc[3]) * inv;
      outstage[(nt * 16 + l15) * 65 + wv * 16 + mt * 4 + quad] = o;
    }
  }

  // ---------- coalesced full-line write-out
  __syncthreads();
#pragma unroll
  for (int i = 0; i < 16; ++i) {
    int j = i * 256 + tid;
    int c = j >> 6, p = j & 63;
    out[(b * 64 + c) * HWHW + hw0 + p] = outstage[c * 65 + p];
  }
}

extern "C" void kernel_launch(void* const* d_in, const int* in_sizes, int n_in,
                              void* d_out, int out_size, void* d_ws, size_t ws_size,
                              hipStream_t stream) {
  const float* feat_supp = (const float*)d_in[0];
  const float* flow      = (const float*)d_in[1];
  const float* feat_curr = (const float*)d_in[2];
  const float* q_w = (const float*)d_in[3];
  const float* q_b = (const float*)d_in[4];
  const float* k_w = (const float*)d_in[5];
  const float* k_b = (const float*)d_in[6];
  const float* v_w = (const float*)d_in[7];
  const float* v_b = (const float*)d_in[8];
  float* out = (float*)d_out;
  (void)in_sizes; (void)n_in; (void)out_size; (void)ws_size;

  __hip_bfloat16* wfrag = (__hip_bfloat16*)d_ws;
  float* bias           = (float*)((char*)d_ws + 32768);
  __hip_bfloat16* suppT = (__hip_bfloat16*)((char*)d_ws + 65536);

  hipLaunchKernelGGL(pre_pass, dim3(2057), dim3(256), 0, stream,
                     feat_supp, q_w, k_w, v_w, k_b, v_b, suppT, wfrag, bias);
  hipLaunchKernelGGL(iw_main, dim3(2048), dim3(256), 0, stream,
                     suppT, flow, feat_curr, (const short8*)d_ws, bias, q_b, out);
}